// Round 10
// baseline (84.479 us; speedup 1.0000x reference)
//
#include <hip/hip_runtime.h>
#include <math.h>

#define SS 8
#define CC 16
#define HH 64
#define WW 96
#define DD 64
#define NN (HH*WW)
#define PW 100            // padded width: 2 zero cols each side
#define PH 66             // padded height: 1 zero row each side
#define PN (PH*PW)        // 6600 padded pixels per source
#define TXC 12            // tiles in x
#define TYC 8             // tiles in y
#define NBLK ((DD/4)*TXC*TYC)     // 1536 cost blocks
#define NBOXW (TXC*TYC*2*(DD/2)*SS)   // 49152 per-(halftile,depthpair,src) boxes
#define BR 8              // staged rows per wave
#define BCU 32            // 16B units per row (16 texels x 32B)

typedef _Float16 h2 __attribute__((ext_vector_type(2)));
struct alignas(16) H8 { h2 v[4]; };   // 8 halfs = 16 B

typedef const __attribute__((address_space(1))) unsigned int gu32;
typedef __attribute__((address_space(3))) unsigned int lu32;

// Folded projection matrix for source s: mo[0..8]=3x3 (pix->ray), mo[9..11]=t.
__device__ __forceinline__ void compute_mat(int s, const float* Ks, const float* ext,
                                            const float* invK, float* mo)
{
    float P[3][4];
    for (int i = 0; i < 3; ++i)
        for (int j = 0; j < 4; ++j) {
            float a = 0.f;
            for (int k = 0; k < 4; ++k)
                a += Ks[s * 16 + i * 4 + k] * ext[s * 16 + k * 4 + j];
            P[i][j] = a;
        }
    for (int i = 0; i < 3; ++i) {
        for (int j = 0; j < 3; ++j) {
            float a = 0.f;
            for (int k = 0; k < 3; ++k)
                a += P[i][k] * invK[k * 4 + j];
            mo[i * 3 + j] = a;
        }
        mo[9 + i] = P[i][3];
    }
}

// Prep: (1) transpose+convert src -> f16 zero-padded channel-last (S,PH,PW,C),
// cur -> (H,W,C); (2) mats + 64 log depths; (3) per-(HALF-TILE 4x8 px,
// DEPTH-PAIR, src) analytic tap boxes: u,v projective over (X,Y,D) with pz>0
// (corner-min + 1e-3 margin) -> extrema at the 8 box corners; +-1 texel fp
// margin. Encoded: xlo|ylo<<7|fit<<14|skip<<15. Fit = 16-texel x 8-row box.
__global__ __launch_bounds__(256) void prep_kernel(
    const float* __restrict__ cur, const float* __restrict__ src,
    const float* __restrict__ ext, const float* __restrict__ Ks,
    const float* __restrict__ invK, const float* __restrict__ mnp,
    const float* __restrict__ mxp,
    _Float16* __restrict__ srcT, _Float16* __restrict__ curT,
    float* __restrict__ mats, float* __restrict__ depths,
    unsigned* __restrict__ boxes)
{
    int tid = blockIdx.x * 256 + threadIdx.x;
    const int srcPad = SS * PN;             // 52800
    if (tid < srcPad) {
        int s = tid / PN;
        int rem = tid % PN;
        int py = rem / PW;
        int px = rem % PW;
        _Float16 v[CC] = {};                // zeros for border texels
        if (py >= 1 && py <= HH && px >= 2 && px <= WW + 1) {
            int p = (py - 1) * WW + (px - 2);
            const float* base = src + (size_t)s * CC * NN + p;
#pragma unroll
            for (int c = 0; c < CC; ++c) v[c] = (_Float16)base[c * NN];
        }
        H8* o = (H8*)(srcT + (size_t)tid * CC);
        o[0] = *(H8*)&v[0];
        o[1] = *(H8*)&v[8];
    } else if (tid < srcPad + NN) {
        int p = tid - srcPad;
        const float* base = cur + p;
        _Float16 v[CC];
#pragma unroll
        for (int c = 0; c < CC; ++c) v[c] = (_Float16)base[c * NN];
        H8* o = (H8*)(curT + (size_t)p * CC);
        o[0] = *(H8*)&v[0];
        o[1] = *(H8*)&v[8];
    } else if (tid < srcPad + NN + NBOXW) {
        int idx = tid - (srcPad + NN);
        int s    = idx & 7;
        int t    = idx >> 3;
        int dgp  = t & 31;                  // depth pair 0..31 (depths 2dgp,2dgp+1)
        int t2   = t >> 5;
        int h    = t2 & 1;                  // half-tile (rows 4h..4h+3)
        int tile = t2 >> 1;                 // 0..95
        int tyi = tile / TXC;
        int txi = tile % TXC;
        float mm[12];
        compute_mat(s, Ks, ext, invK, mm);
        float lmn = logf(mnp[0]);
        float lr  = logf(mxp[0] / mnp[0]);
        float D0 = expf(lmn + lr * ((float)(2 * dgp)     * (1.0f / (DD - 1))));
        float D1 = expf(lmn + lr * ((float)(2 * dgp + 1) * (1.0f / (DD - 1))));
        float xs0 = txi * 8 + 0.5f, xs1 = txi * 8 + 7.5f;
        float ys0 = tyi * 8 + h * 4 + 0.5f, ys1 = ys0 + 3.0f;
        float pzmin = 1e30f, pzmax = -1e30f;
        float umin = 1e30f, umax = -1e30f, vmin = 1e30f, vmax = -1e30f;
        int x0min = 999, x0max = -999, y0min = 999, y1max = -999;
        for (int ci = 0; ci < 8; ++ci) {
            float X  = (ci & 1) ? xs1 : xs0;
            float Y  = (ci & 2) ? ys1 : ys0;
            float Dp = (ci & 4) ? D1  : D0;
            float qx = mm[0] * X + mm[1] * Y + mm[2];
            float qy = mm[3] * X + mm[4] * Y + mm[5];
            float qz = mm[6] * X + mm[7] * Y + mm[8];
            float pz = Dp * qz + mm[11];
            pzmin = fminf(pzmin, pz); pzmax = fmaxf(pzmax, pz);
            float r = __builtin_amdgcn_rcpf(pz + 1e-8f);   // mirror px math
            float u = (Dp * qx + mm[9])  * r - 0.5f;
            float v = (Dp * qy + mm[10]) * r - 0.5f;
            umin = fminf(umin, u); umax = fmaxf(umax, u);
            vmin = fminf(vmin, v); vmax = fmaxf(vmax, v);
            float ucc = fminf(fmaxf(u, -2.0f), 96.5f);
            float vcc = fminf(fmaxf(v, -1.0f), 64.5f);
            int x0c = (int)floorf(ucc) + 2;
            int y0c = (int)floorf(vcc) + 1;
            int y1c = min(y0c + 1, PH - 1);
            x0min = min(x0min, x0c); x0max = max(x0max, x0c);
            y0min = min(y0min, y0c); y1max = max(y1max, y1c);
        }
        bool allpz = pzmin > 1e-3f;          // margin: interior fp-eval surely > 0
        bool skip  = (pzmax <= 0.f) ||
                     (allpz && (umax < -1.01f || umin > 96.01f ||
                                vmax < -1.01f || vmin > 64.01f));
        int xlo = 0, ylo = 0; bool fit = false;
        if (allpz) {
            xlo = min(max(x0min - 1, 0), PW - 16);   // <=84: 16 texels in-image
            ylo = min(max(y0min - 1, 0), PH - BR);   // <=58: 8 rows in-image
            fit = (x0max + 1 - xlo <= 15)            // right tap within 16 texels
               && (y1max - ylo <= 7);                // both rows within 8
        }
        boxes[idx] = (unsigned)xlo | ((unsigned)ylo << 7)
                   | (fit ? 1u << 14 : 0u) | (skip ? 1u << 15 : 0u);
    }
    if (blockIdx.x == 0) {
        if (threadIdx.x < DD) {
            float lmn = logf(mnp[0]);
            float lr  = logf(mxp[0] / mnp[0]);
            depths[threadIdx.x] = expf(lmn + lr * ((float)threadIdx.x * (1.0f / (DD - 1))));
        } else if (threadIdx.x < DD + SS) {
            int s = threadIdx.x - DD;
            float mm[12];
            compute_mat(s, Ks, ext, invK, mm);
            for (int i = 0; i < 12; ++i) mats[s * 12 + i] = mm[i];
        }
    }
}

// Main: block = 8x8 tile x 4 depths; wave = HALF-TILE (32 px) x 2 CONSECUTIVE
// DEPTHS (lane = dloc*32 + p32). Measured model (R0/R4/R8/R9 all ~equal at 8
// VMEM instrs; R3/R5 slower only via occupancy): VMEM costs ~60cy per wave64
// instruction regardless of address pattern -> the only lever is FEWER
// instructions = dedup. The 2-depth union tap-box fits 16 texels x 8 rows for
// ~83% of (pair,src) cells -> 4 DMAs replace 8 gathers (2x). Wave-private
// vmcnt(0) (no barriers, R7's disease); gather fallback when unfit; LDS reads
// XOR-swizzled via pre-swizzled global source (linear DMA dest, rule #21).
__global__ __launch_bounds__(256, 6) void cost_kernel(
    const _Float16* __restrict__ curT, const _Float16* __restrict__ srcT,
    const float* __restrict__ mats, const float* __restrict__ depths,
    const unsigned* __restrict__ boxes, float* __restrict__ out)
{
    __shared__ H8 stage[4][BR][BCU];       // 4 waves x 8 rows x 512B = 16 KB

    int tid = threadIdx.x;
    int bx = blockIdx.x;
    int dg  = bx / (TXC * TYC);            // depth group of 4
    int rem = bx % (TXC * TYC);            // tile index 0..95
    int tyi = rem / TXC;
    int txi = rem % TXC;
    int w    = tid >> 6;                   // wave 0..3
    int h    = w & 1;                      // half-tile
    int pr   = w >> 1;                     // depth pair within group
    int lane = tid & 63;
    int dloc = lane >> 5;                  // depth within pair
    int p32  = lane & 31;                  // pixel within half-tile
    int px = txi * 8 + (p32 & 7);
    int py = tyi * 8 + h * 4 + (p32 >> 3);
    int n  = py * WW + px;

    float x = (float)px + 0.5f;
    float y = (float)py + 0.5f;

    const H8* cp = (const H8*)(curT + (size_t)n * CC);
    H8 cA = cp[0], cB = cp[1];
    int dbase = __builtin_amdgcn_readfirstlane(dg * 4 + pr * 2);
    float dep0 = depths[dbase], dep1 = depths[dbase + 1];   // scalar loads
    float depth = dloc ? dep1 : dep0;
    int d = dbase + dloc;
    const unsigned* bb = boxes + ((size_t)((rem * 2 + h) * 32 + (dg * 2 + pr))) * SS;

    float acc = 0.f;
#pragma unroll 1
    for (int s = 0; s < SS; ++s) {
        unsigned bw = bb[s];               // wave-uniform scalar
        if (bw & (1u << 15)) continue;     // exact 0 for the whole wave
        bool fit = (bw & (1u << 14)) != 0;
        int xlo = bw & 127, ylo = (bw >> 7) & 127;
        const _Float16* sb = srcT + (size_t)s * (PN * CC);

        if (fit) {
            // 4 DMAs stage the 16-texel x 8-row union box for all 64 lane-outputs.
            // Source pre-swizzled (unit u of row r holds texel-unit u^((r&7)<<2))
            // so same-column different-row LDS reads land on distinct banks.
            asm volatile("" ::: "memory");  // keep DMA issue after prior LDS reads
#pragma unroll
            for (int k = 0; k < 4; ++k) {
                int r  = 2 * k + (lane >> 5);
                int cu = (lane & 31) ^ ((r & 7) << 2);
                const _Float16* gsrc = sb + ((size_t)((ylo + r) * PW + xlo)) * CC + cu * 8;
                __builtin_amdgcn_global_load_lds((gu32*)gsrc,
                                                 (lu32*)&stage[w][2 * k][0], 16, 0, 0);
            }
        }

        const float* m = &mats[s * 12];    // s loop-uniform -> s_load
        float m0 = m[0], m1 = m[1], m2 = m[2], m3 = m[3], m4 = m[4], m5 = m[5];
        float m6 = m[6], m7 = m[7], m8 = m[8], m9 = m[9], m10 = m[10], m11 = m[11];
        float qx = m0 * x + m1 * y + m2;
        float qy = m3 * x + m4 * y + m5;
        float qz = m6 * x + m7 * y + m8;
        float pz = depth * qz + m11;
        bool ok = pz > 0.f;
        float rr = __builtin_amdgcn_rcpf(pz + 1e-8f);  // u = px/(z+EPS) per ref
        float u = (depth * qx + m9)  * rr - 0.5f;
        float v = (depth * qy + m10) * rr - 0.5f;
        float uc = ok ? fminf(fmaxf(u, -2.0f), 96.5f) : -2.0f;
        float vc = ok ? fminf(fmaxf(v, -1.0f), 64.5f) : -1.0f;
        float x0f = floorf(uc), y0f = floorf(vc);
        float wx = uc - x0f, wy = vc - y0f;
        int x0p = (int)x0f + 2;                  // [0, 98]
        int y0p = (int)y0f + 1;                  // [0, 65]
        int y1p = min(y0p + 1, PH - 1);          // [1, 65]

        H8 a0, a1, a2, a3, b0, b1, b2, b3;
        if (fit) {
            // wave-private wait for our own DMAs; other waves unaffected
            asm volatile("s_waitcnt vmcnt(0)" ::: "memory");
            int u0  = 2 * (x0p - xlo);           // 0..28 (corner-proven)
            int ry0 = y0p - ylo;                 // 0..6
            int ry1 = y1p - ylo;                 // 1..7
            int s0 = (ry0 & 7) << 2, s1 = (ry1 & 7) << 2;
            const H8* Wv = &stage[w][0][0];
            a0 = Wv[ry0 * BCU + ((u0    ) ^ s0)];
            a1 = Wv[ry0 * BCU + ((u0 + 1) ^ s0)];
            a2 = Wv[ry0 * BCU + ((u0 + 2) ^ s0)];
            a3 = Wv[ry0 * BCU + ((u0 + 3) ^ s0)];
            b0 = Wv[ry1 * BCU + ((u0    ) ^ s1)];
            b1 = Wv[ry1 * BCU + ((u0 + 1) ^ s1)];
            b2 = Wv[ry1 * BCU + ((u0 + 2) ^ s1)];
            b3 = Wv[ry1 * BCU + ((u0 + 3) ^ s1)];
        } else {
            // fallback: verified R0 direct gathers
            bool contrib = ok && (u > -1.f) && (u < (float)WW) && (v > -1.f) && (v < (float)HH);
            if (__ballot(contrib) == 0ull) continue;
            const H8* r0 = (const H8*)(sb + (size_t)(y0p * PW + x0p) * CC);
            const H8* r1 = (const H8*)(sb + (size_t)(y1p * PW + x0p) * CC);
            a0 = r0[0]; a1 = r0[1]; a2 = r0[2]; a3 = r0[3];
            b0 = r1[0]; b1 = r1[1]; b2 = r1[2]; b3 = r1[3];
        }
        float dL0 = 0.f, dR0 = 0.f, dL1 = 0.f, dR1 = 0.f;
#pragma unroll
        for (int q = 0; q < 4; ++q) {
            dL0 = __builtin_amdgcn_fdot2(a0.v[q], cA.v[q], dL0, false);
            dL0 = __builtin_amdgcn_fdot2(a1.v[q], cB.v[q], dL0, false);
            dR0 = __builtin_amdgcn_fdot2(a2.v[q], cA.v[q], dR0, false);
            dR0 = __builtin_amdgcn_fdot2(a3.v[q], cB.v[q], dR0, false);
            dL1 = __builtin_amdgcn_fdot2(b0.v[q], cA.v[q], dL1, false);
            dL1 = __builtin_amdgcn_fdot2(b1.v[q], cB.v[q], dL1, false);
            dR1 = __builtin_amdgcn_fdot2(b2.v[q], cA.v[q], dR1, false);
            dR1 = __builtin_amdgcn_fdot2(b3.v[q], cB.v[q], dR1, false);
        }
        float d0 = dL0 + wx * (dR0 - dL0);
        float d1 = dL1 + wx * (dR1 - dL1);
        acc += d0 + wy * (d1 - d0);
    }
    out[(size_t)d * NN + n] = acc;                      // cost_volume
    out[(size_t)DD * NN + (size_t)d * NN + n] = depth;  // depth_planes
}

extern "C" void kernel_launch(void* const* d_in, const int* in_sizes, int n_in,
                              void* d_out, int out_size, void* d_ws, size_t ws_size,
                              hipStream_t stream) {
    const float* cur  = (const float*)d_in[0];
    const float* src  = (const float*)d_in[1];
    const float* ext  = (const float*)d_in[2];
    const float* Ks   = (const float*)d_in[3];
    const float* invK = (const float*)d_in[4];
    const float* mn   = (const float*)d_in[5];
    const float* mx   = (const float*)d_in[6];
    float* out = (float*)d_out;

    char* ws = (char*)d_ws;
    _Float16* srcT = (_Float16*)ws;                     // S*PN*C halfs ≈ 1.69 MB
    _Float16* curT = srcT + (size_t)SS * PN * CC;       // N*C halfs
    float* mats    = (float*)(curT + (size_t)NN * CC);  // 96
    float* depths  = mats + SS * 12;                    // 64
    unsigned* boxes = (unsigned*)(depths + DD);         // 49152 u32 = 192 KB

    int prepThreads = SS * PN + NN + NBOXW;             // 108096
    int prepBlocks = (prepThreads + 255) / 256;         // 423
    prep_kernel<<<prepBlocks, 256, 0, stream>>>(cur, src, ext, Ks, invK, mn, mx,
                                                srcT, curT, mats, depths, boxes);
    cost_kernel<<<NBLK, 256, 0, stream>>>(curT, srcT, mats, depths, boxes, out);
}

// Round 11
// 82.280 us; speedup vs baseline: 1.0267x; 1.0267x over previous
//
#include <hip/hip_runtime.h>
#include <math.h>

#define SS 8
#define CC 16
#define HH 64
#define WW 96
#define DD 64
#define NN (HH*WW)
#define PW 100            // padded width: 2 zero cols each side
#define PH 66             // padded height: 1 zero row each side
#define PN (PH*PW)        // 6600 padded pixels per source

typedef _Float16 h2 __attribute__((ext_vector_type(2)));
struct alignas(16) H8 { h2 v[4]; };   // 8 halfs = 16 B

// Prep: transpose+convert src (S,C,H,W) -> f16 zero-padded channel-last
// (S, PH, PW, C); cur (C,H,W) -> f16 (H,W,C). Border texels written as zeros
// so OOB bilinear taps read 0 with no per-tap masking in the main kernel.
// Also folded projection matrices and the 64 log-spaced depths.
__global__ __launch_bounds__(256) void prep_kernel(
    const float* __restrict__ cur, const float* __restrict__ src,
    const float* __restrict__ ext, const float* __restrict__ Ks,
    const float* __restrict__ invK, const float* __restrict__ mnp,
    const float* __restrict__ mxp,
    _Float16* __restrict__ srcT, _Float16* __restrict__ curT,
    float* __restrict__ mats, float* __restrict__ depths)
{
    int tid = blockIdx.x * 256 + threadIdx.x;
    const int srcPad = SS * PN;             // 52800
    if (tid < srcPad) {
        int s = tid / PN;
        int rem = tid % PN;
        int py = rem / PW;
        int px = rem % PW;
        _Float16 v[CC] = {};                // zeros for border texels
        if (py >= 1 && py <= HH && px >= 2 && px <= WW + 1) {
            int p = (py - 1) * WW + (px - 2);
            const float* base = src + (size_t)s * CC * NN + p;
#pragma unroll
            for (int c = 0; c < CC; ++c) v[c] = (_Float16)base[c * NN];
        }
        H8* o = (H8*)(srcT + (size_t)tid * CC);
        o[0] = *(H8*)&v[0];
        o[1] = *(H8*)&v[8];
    } else if (tid < srcPad + NN) {
        int p = tid - srcPad;
        const float* base = cur + p;
        _Float16 v[CC];
#pragma unroll
        for (int c = 0; c < CC; ++c) v[c] = (_Float16)base[c * NN];
        H8* o = (H8*)(curT + (size_t)p * CC);
        o[0] = *(H8*)&v[0];
        o[1] = *(H8*)&v[8];
    }
    if (blockIdx.x == 0) {
        if (threadIdx.x < DD) {
            float lmn = logf(mnp[0]);
            float lr  = logf(mxp[0] / mnp[0]);
            depths[threadIdx.x] = expf(lmn + lr * ((float)threadIdx.x * (1.0f / (DD - 1))));
        } else if (threadIdx.x < DD + SS) {
            int s = threadIdx.x - DD;
            float P[3][4];
            for (int i = 0; i < 3; ++i)
                for (int j = 0; j < 4; ++j) {
                    float a = 0.f;
                    for (int k = 0; k < 4; ++k)
                        a += Ks[s * 16 + i * 4 + k] * ext[s * 16 + k * 4 + j];
                    P[i][j] = a;
                }
            for (int i = 0; i < 3; ++i) {
                for (int j = 0; j < 3; ++j) {
                    float a = 0.f;
                    for (int k = 0; k < 3; ++k)
                        a += P[i][k] * invK[k * 4 + j];
                    mats[s * 12 + i * 3 + j] = a;
                }
                mats[s * 12 + 9 + i] = P[i][3];
            }
        }
    }
}

// Main: best-measured variant across the session (81.9us, R6). Verified R0
// structure: block = 8x8 pixel tile x 4 depths (one depth per wave), 8 direct
// 16B gathers + 16 fdot2 per source, per-lane zero-border clamps, LB(256,8).
// Session evidence for why this simple form is the floor: VMEM instr count
// (8/7/4), coalescing (gather vs global_load_lds), lane mapping (3 variants),
// LDS staging (3 sync schemes), and occupancy >24 waves/CU were ALL measured
// neutral-or-worse (R1-R10); the ~38us cost floor is a latency/issue
// structural property of 12K short dependent-chain iterations, not a
// saturated pipe.
__global__ __launch_bounds__(256, 8) void cost_kernel(
    const _Float16* __restrict__ curT, const _Float16* __restrict__ srcT,
    const float* __restrict__ mats, const float* __restrict__ depths,
    float* __restrict__ out)
{
    int tid = threadIdx.x;
    const int TX = WW / 8;                 // 12
    const int TY = HH / 8;                 // 8
    int bx = blockIdx.x;
    int dg  = bx / (TX * TY);              // 0..15
    int rem = bx % (TX * TY);
    int tyi = rem / TX;
    int txi = rem % TX;
    int lane = tid & 63;
    int dsub = tid >> 6;                   // wave index = depth sub-index
    int d  = dg * 4 + dsub;
    int px = txi * 8 + (lane & 7);
    int py = tyi * 8 + (lane >> 3);
    int n  = py * WW + px;

    float x = (float)px + 0.5f;
    float y = (float)py + 0.5f;

    const H8* cp = (const H8*)(curT + (size_t)n * CC);
    H8 cA = cp[0], cB = cp[1];
    // d is wave-uniform; force scalar load of the depth
    float depth = depths[__builtin_amdgcn_readfirstlane(d)];

    float acc = 0.f;
#pragma unroll 1
    for (int s = 0; s < SS; ++s) {
        const float* m = &mats[s * 12];    // s loop-uniform -> s_load
        float m0 = m[0], m1 = m[1], m2 = m[2], m3 = m[3], m4 = m[4], m5 = m[5];
        float m6 = m[6], m7 = m[7], m8 = m[8], m9 = m[9], m10 = m[10], m11 = m[11];
        float qx = m0 * x + m1 * y + m2;
        float qy = m3 * x + m4 * y + m5;
        float qz = m6 * x + m7 * y + m8;
        float pz = depth * qz + m11;
        bool ok = pz > 0.f;
        float r = __builtin_amdgcn_rcpf(pz + 1e-8f);   // u = px/(z+EPS) per ref
        float u = (depth * qx + m9)  * r - 0.5f;
        float v = (depth * qy + m10) * r - 0.5f;
        // wave-uniform skip: contribution is exactly 0 when z<=0 or all 4 taps OOB
        bool contrib = ok && (u > -1.f) && (u < (float)WW) && (v > -1.f) && (v < (float)HH);
        if (__ballot(contrib) == 0ull) continue;
        // float-side clamps keep both taps of each pair inside the padded image
        // and in the zero border when OOB (v_med3_f32); !ok -> far border
        float uc = ok ? fminf(fmaxf(u, -2.0f), 96.5f) : -2.0f;
        float vc = ok ? fminf(fmaxf(v, -1.0f), 64.5f) : -1.0f;
        float x0f = floorf(uc), y0f = floorf(vc);
        float wx = uc - x0f, wy = vc - y0f;
        int x0p = (int)x0f + 2;                  // [0, 98]
        int y0p = (int)y0f + 1;                  // [0, 65]
        int y1p = min(y0p + 1, PH - 1);          // [1, 65]
        const _Float16* sbase = srcT + (size_t)s * (PN * CC);
        const H8* r0 = (const H8*)(sbase + (size_t)(y0p * PW + x0p) * CC);
        const H8* r1 = (const H8*)(sbase + (size_t)(y1p * PW + x0p) * CC);
        H8 a0 = r0[0], a1 = r0[1], a2 = r0[2], a3 = r0[3];   // row0: left|right tap
        H8 b0 = r1[0], b1 = r1[1], b2 = r1[2], b3 = r1[3];   // row1: left|right tap
        float dL0 = 0.f, dR0 = 0.f, dL1 = 0.f, dR1 = 0.f;
#pragma unroll
        for (int q = 0; q < 4; ++q) {
            dL0 = __builtin_amdgcn_fdot2(a0.v[q], cA.v[q], dL0, false);
            dL0 = __builtin_amdgcn_fdot2(a1.v[q], cB.v[q], dL0, false);
            dR0 = __builtin_amdgcn_fdot2(a2.v[q], cA.v[q], dR0, false);
            dR0 = __builtin_amdgcn_fdot2(a3.v[q], cB.v[q], dR0, false);
            dL1 = __builtin_amdgcn_fdot2(b0.v[q], cA.v[q], dL1, false);
            dL1 = __builtin_amdgcn_fdot2(b1.v[q], cB.v[q], dL1, false);
            dR1 = __builtin_amdgcn_fdot2(b2.v[q], cA.v[q], dR1, false);
            dR1 = __builtin_amdgcn_fdot2(b3.v[q], cB.v[q], dR1, false);
        }
        float d0 = dL0 + wx * (dR0 - dL0);
        float d1 = dL1 + wx * (dR1 - dL1);
        acc += d0 + wy * (d1 - d0);
    }
    out[(size_t)d * NN + n] = acc;                      // cost_volume
    out[(size_t)DD * NN + (size_t)d * NN + n] = depth;  // depth_planes
}

extern "C" void kernel_launch(void* const* d_in, const int* in_sizes, int n_in,
                              void* d_out, int out_size, void* d_ws, size_t ws_size,
                              hipStream_t stream) {
    const float* cur  = (const float*)d_in[0];
    const float* src  = (const float*)d_in[1];
    const float* ext  = (const float*)d_in[2];
    const float* Ks   = (const float*)d_in[3];
    const float* invK = (const float*)d_in[4];
    const float* mn   = (const float*)d_in[5];
    const float* mx   = (const float*)d_in[6];
    float* out = (float*)d_out;

    char* ws = (char*)d_ws;
    _Float16* srcT = (_Float16*)ws;                     // S*PN*C halfs ≈ 1.69 MB
    _Float16* curT = srcT + (size_t)SS * PN * CC;       // N*C halfs
    float* mats    = (float*)(curT + (size_t)NN * CC);  // 96
    float* depths  = mats + SS * 12;                    // 64

    int prepThreads = SS * PN + NN;                     // 58944
    int prepBlocks = (prepThreads + 255) / 256;         // 231
    prep_kernel<<<prepBlocks, 256, 0, stream>>>(cur, src, ext, Ks, invK, mn, mx,
                                                srcT, curT, mats, depths);
    cost_kernel<<<(DD / 4) * (WW / 8) * (HH / 8), 256, 0, stream>>>(curT, srcT, mats, depths, out);
}